// Round 1
// baseline (3309.869 us; speedup 1.0000x reference)
//
#include <hip/hip_runtime.h>
#include <cmath>

#define F_IN 128
#define HDIM 64

// ---------------- degree / norm ----------------

__global__ void init_deg(float* deg, int n) {
    int i = blockIdx.x * blockDim.x + threadIdx.x;
    if (i < n) deg[i] = 1.0f;  // self-loop contributes 1
}

__global__ void deg_accum(const int* __restrict__ dst, float* deg, int E) {
    int e = blockIdx.x * blockDim.x + threadIdx.x;
    if (e < E) atomicAdd(deg + dst[e], 1.0f);
}

__global__ void make_dinv(float* deg, int n) {
    int i = blockIdx.x * blockDim.x + threadIdx.x;
    if (i < n) deg[i] = rsqrtf(deg[i]);  // deg >= 1 always (self-loops)
}

__global__ void make_norm(const int* __restrict__ src, const int* __restrict__ dst,
                          const float* __restrict__ dinv, float* __restrict__ norm, int E) {
    int e = blockIdx.x * blockDim.x + threadIdx.x;
    if (e < E) norm[e] = dinv[src[e]] * dinv[dst[e]];
}

// ---------------- dense matmul  out[n,64] = X[n,K] @ W[K,64] ----------------

template <int K>
__launch_bounds__(512)
__global__ void matmul_nn(const float* __restrict__ X, const float* __restrict__ W,
                          float* __restrict__ out, int n) {
    __shared__ float Wl[K * HDIM];
    __shared__ float Xl[8 * K];
    int tid = threadIdx.x;
    for (int i = tid; i < K * HDIM; i += 512) Wl[i] = W[i];
    int base = blockIdx.x * 8;
    for (int i = tid; i < 8 * K; i += 512) {
        int gr = base + i / K;
        Xl[i] = (gr < n) ? X[(size_t)base * K + i] : 0.0f;
    }
    __syncthreads();
    int r = tid >> 6;       // 0..7
    int col = tid & 63;     // 0..63
    int row = base + r;
    if (row >= n) return;
    const float* xr = Xl + r * K;
    float acc = 0.0f;
#pragma unroll
    for (int k = 0; k < K; ++k) acc = fmaf(xr[k], Wl[k * HDIM + col], acc);
    out[(size_t)row * HDIM + col] = acc;
}

// ---------------- self-loop init: agg[i] = xw[i] * dinv[i]^2 ----------------

__global__ void self_init(const float* __restrict__ xw, const float* __restrict__ dinv,
                          float* __restrict__ agg, int n) {
    int idx = blockIdx.x * blockDim.x + threadIdx.x;
    if (idx >= n * 16) return;
    int i = idx >> 4, fo = (idx & 15) << 2;
    float di = dinv[i];
    float s = di * di;
    float4 v = *(const float4*)(xw + (size_t)i * HDIM + fo);
    float4 o;
    o.x = v.x * s; o.y = v.y * s; o.z = v.z * s; o.w = v.w * s;
    *(float4*)(agg + (size_t)i * HDIM + fo) = o;
}

// ---------------- edge aggregation: agg[dst] += xw[src] * norm ----------------

__global__ void aggregate(const int* __restrict__ src, const int* __restrict__ dst,
                          const float* __restrict__ norm, const float* __restrict__ xw,
                          float* agg, int E) {
    int idx = blockIdx.x * blockDim.x + threadIdx.x;   // E*16 threads
    int e = idx >> 4;
    if (e >= E) return;
    int fo = (idx & 15) << 2;
    int s = src[e], d = dst[e];
    float nm = norm[e];
    float4 v = *(const float4*)(xw + (size_t)s * HDIM + fo);
    float* p = agg + (size_t)d * HDIM + fo;
    atomicAdd(p + 0, v.x * nm);
    atomicAdd(p + 1, v.y * nm);
    atomicAdd(p + 2, v.z * nm);
    atomicAdd(p + 3, v.w * nm);
}

// ---------------- bias + relu (in place) ----------------

__global__ void bias_relu(float* h, const float* __restrict__ b, int n) {
    int idx = blockIdx.x * blockDim.x + threadIdx.x;
    if (idx >= n * 16) return;
    int i = idx >> 4, fo = (idx & 15) << 2;
    float4 v = *(float4*)(h + (size_t)i * HDIM + fo);
    v.x = fmaxf(v.x + b[fo + 0], 0.0f);
    v.y = fmaxf(v.y + b[fo + 1], 0.0f);
    v.z = fmaxf(v.z + b[fo + 2], 0.0f);
    v.w = fmaxf(v.w + b[fo + 3], 0.0f);
    *(float4*)(h + (size_t)i * HDIM + fo) = v;
}

// ---------------- pooling ----------------

__global__ void pool_zero(float* pooled, float* cnt, int G) {
    int idx = blockIdx.x * blockDim.x + threadIdx.x;
    if (idx < G * HDIM) pooled[idx] = 0.0f;
    if (idx < G) cnt[idx] = 0.0f;
}

__global__ void pool_accum(const float* __restrict__ h, const int* __restrict__ batch,
                           float* pooled, float* cnt, int n) {
    int idx = blockIdx.x * blockDim.x + threadIdx.x;
    if (idx >= n * 16) return;
    int i = idx >> 4, fo = (idx & 15) << 2;
    int g = batch[i];
    float4 v = *(const float4*)(h + (size_t)i * HDIM + fo);
    float* p = pooled + (size_t)g * HDIM + fo;
    atomicAdd(p + 0, v.x);
    atomicAdd(p + 1, v.y);
    atomicAdd(p + 2, v.z);
    atomicAdd(p + 3, v.w);
    if ((idx & 15) == 0) atomicAdd(cnt + g, 1.0f);
}

// ---------------- head: sigmoid(mean @ Wl + bl) ----------------

__global__ void final_head(const float* __restrict__ pooled, const float* __restrict__ cnt,
                           const float* __restrict__ Wl, const float* __restrict__ bl,
                           float* out, int G) {
    int g = blockIdx.x * (blockDim.x >> 6) + (threadIdx.x >> 6);
    int lane = threadIdx.x & 63;
    if (g >= G) return;
    float c = fmaxf(cnt[g], 1.0f);
    float v = pooled[(size_t)g * HDIM + lane] * (1.0f / c) * Wl[lane];
#pragma unroll
    for (int off = 32; off; off >>= 1) v += __shfl_down(v, off, 64);
    if (lane == 0) out[g] = 1.0f / (1.0f + expf(-(v + bl[0])));
}

// ---------------- launch ----------------

extern "C" void kernel_launch(void* const* d_in, const int* in_sizes, int n_in,
                              void* d_out, int out_size, void* d_ws, size_t ws_size,
                              hipStream_t stream) {
    const float* x  = (const float*)d_in[0];
    const int* ei   = (const int*)d_in[1];
    const int* batch = (const int*)d_in[2];
    const float* W1 = (const float*)d_in[3];
    const float* b1 = (const float*)d_in[4];
    const float* W2 = (const float*)d_in[5];
    const float* b2 = (const float*)d_in[6];
    const float* Wl = (const float*)d_in[7];
    const float* bl = (const float*)d_in[8];
    float* out = (float*)d_out;

    const int n = in_sizes[0] / F_IN;   // 100000
    const int E = in_sizes[1] / 2;      // 1600000
    const int G = out_size;             // 512

    const int* srcp = ei;
    const int* dstp = ei + E;

    // workspace layout (floats)
    float* ws = (float*)d_ws;
    float* dinv = ws;                                   // n (deg -> dinv in place)
    size_t off = ((size_t)n + 127) & ~(size_t)127;
    float* bufA   = ws + off;                           // n*64  (xw)
    float* bufB   = bufA + (size_t)n * HDIM;            // n*64  (agg / h)
    float* pooled = bufB + (size_t)n * HDIM;            // G*64
    float* cnt    = pooled + (size_t)G * HDIM;          // G
    float* enorm  = cnt + G;                            // E

    const int TB = 256;
    int gN   = (n + TB - 1) / TB;
    int gE   = (E + TB - 1) / TB;
    int gN16 = (n * 16 + TB - 1) / TB;
    int gE16 = (int)(((long long)E * 16 + TB - 1) / TB);
    int gMM  = (n + 7) / 8;

    // degree -> dinv -> per-edge norm
    init_deg<<<gN, TB, 0, stream>>>(dinv, n);
    deg_accum<<<gE, TB, 0, stream>>>(dstp, dinv, E);
    make_dinv<<<gN, TB, 0, stream>>>(dinv, n);
    make_norm<<<gE, TB, 0, stream>>>(srcp, dstp, dinv, enorm, E);

    // layer 1
    matmul_nn<F_IN><<<gMM, 512, 0, stream>>>(x, W1, bufA, n);
    self_init<<<gN16, TB, 0, stream>>>(bufA, dinv, bufB, n);
    aggregate<<<gE16, TB, 0, stream>>>(srcp, dstp, enorm, bufA, bufB, E);
    bias_relu<<<gN16, TB, 0, stream>>>(bufB, b1, n);

    // layer 2
    matmul_nn<HDIM><<<gMM, 512, 0, stream>>>(bufB, W2, bufA, n);
    self_init<<<gN16, TB, 0, stream>>>(bufA, dinv, bufB, n);
    aggregate<<<gE16, TB, 0, stream>>>(srcp, dstp, enorm, bufA, bufB, E);
    bias_relu<<<gN16, TB, 0, stream>>>(bufB, b2, n);

    // pooling + head
    pool_zero<<<(G * HDIM + TB - 1) / TB, TB, 0, stream>>>(pooled, cnt, G);
    pool_accum<<<gN16, TB, 0, stream>>>(bufB, batch, pooled, cnt, n);
    final_head<<<(G + 3) / 4, TB, 0, stream>>>(pooled, cnt, Wl, bl, out, G);
}

// Round 2
// 766.858 us; speedup vs baseline: 4.3161x; 4.3161x over previous
//
#include <hip/hip_runtime.h>
#include <cmath>

#define F_IN 128
#define HDIM 64
#define SCAN_B 256   // elements per scan block

// ---------------- CSR build ----------------

__global__ void zero_ints(int* p, int n) {
    int i = blockIdx.x * blockDim.x + threadIdx.x;
    if (i < n) p[i] = 0;
}

__global__ void count_deg(const int* __restrict__ dst, int* deg, int E) {
    int e = blockIdx.x * blockDim.x + threadIdx.x;
    if (e < E) atomicAdd(deg + dst[e], 1);
}

// block-wise inclusive scan; writes scanned chunk + per-block total
__global__ void scan1(const int* __restrict__ deg, int* __restrict__ tmp,
                      int* __restrict__ partials, int n) {
    __shared__ int sd[SCAN_B];
    int tid = threadIdx.x;
    int i = blockIdx.x * SCAN_B + tid;
    int v = (i < n) ? deg[i] : 0;
    sd[tid] = v;
    __syncthreads();
    for (int off = 1; off < SCAN_B; off <<= 1) {
        int add = (tid >= off) ? sd[tid - off] : 0;
        __syncthreads();
        sd[tid] += add;
        __syncthreads();
    }
    if (i < n) tmp[i] = sd[tid];
    if (tid == SCAN_B - 1) partials[blockIdx.x] = sd[tid];
}

// single-block scan of partials (nb <= 512)
__global__ void scan2(int* partials, int nb) {
    __shared__ int sd[512];
    int tid = threadIdx.x;
    sd[tid] = (tid < nb) ? partials[tid] : 0;
    __syncthreads();
    for (int off = 1; off < 512; off <<= 1) {
        int add = (tid >= off) ? sd[tid - off] : 0;
        __syncthreads();
        sd[tid] += add;
        __syncthreads();
    }
    if (tid < nb) partials[tid] = sd[tid];
}

// finalize: exclusive row_start, cursor copy, dinv = rsqrt(deg+1)
__global__ void scan3(const int* __restrict__ deg, const int* __restrict__ tmp,
                      const int* __restrict__ partials, int* __restrict__ row_start,
                      int* __restrict__ cursor, float* __restrict__ dinv, int n) {
    int i = blockIdx.x * blockDim.x + threadIdx.x;
    if (i >= n) return;
    int b = i / SCAN_B;
    int excl = tmp[i] - deg[i] + (b > 0 ? partials[b - 1] : 0);
    row_start[i] = excl;
    cursor[i] = excl;
    dinv[i] = rsqrtf((float)(deg[i] + 1));
}

__global__ void scatter_edges(const int* __restrict__ src, const int* __restrict__ dst,
                              int* cursor, int* __restrict__ col, int E) {
    int e = blockIdx.x * blockDim.x + threadIdx.x;
    if (e >= E) return;
    int pos = atomicAdd(cursor + dst[e], 1);
    col[pos] = src[e];
}

// ---------------- dense matmul, epilogue scale by dinv[row] ----------------
// out[r, c] = (X @ W)[r, c] * dinv[r]

template <int K>
__launch_bounds__(512)
__global__ void matmul_scaled(const float* __restrict__ X, const float* __restrict__ W,
                              const float* __restrict__ dinv, float* __restrict__ out, int n) {
    __shared__ float Wl[K * HDIM];
    __shared__ float Xl[8 * K];
    int tid = threadIdx.x;
    for (int i = tid; i < K * HDIM; i += 512) Wl[i] = W[i];
    int base = blockIdx.x * 8;
    for (int i = tid; i < 8 * K; i += 512) {
        int gr = base + i / K;
        Xl[i] = (gr < n) ? X[(size_t)base * K + i] : 0.0f;
    }
    __syncthreads();
    int r = tid >> 6;       // 0..7
    int col = tid & 63;     // 0..63
    int row = base + r;
    if (row >= n) return;
    const float* xr = Xl + r * K;
    float acc = 0.0f;
#pragma unroll
    for (int k = 0; k < K; ++k) acc = fmaf(xr[k], Wl[k * HDIM + col], acc);
    out[(size_t)row * HDIM + col] = acc * dinv[row];
}

// ---------------- pull-mode aggregation ----------------
// out[i] = relu(dinv[i] * (xws[i] + sum_{e in row i} xws[col[e]]) + bias)
// 16 lanes per node, one float4 per lane.

__global__ void csr_gather(const int* __restrict__ col, const int* __restrict__ row_start,
                           const int* __restrict__ deg, const float* __restrict__ dinv,
                           const float4* __restrict__ xws, const float* __restrict__ bias,
                           float4* __restrict__ out, int n) {
    int t = blockIdx.x * blockDim.x + threadIdx.x;
    int node = t >> 4;
    if (node >= n) return;
    int lane = t & 15;
    int s = row_start[node];
    int end = s + deg[node];

    float4 acc = xws[(size_t)node * 16 + lane];   // self-loop term
    int e = s;
    for (; e + 4 <= end; e += 4) {
        int c0 = col[e], c1 = col[e + 1], c2 = col[e + 2], c3 = col[e + 3];
        float4 v0 = xws[(size_t)c0 * 16 + lane];
        float4 v1 = xws[(size_t)c1 * 16 + lane];
        float4 v2 = xws[(size_t)c2 * 16 + lane];
        float4 v3 = xws[(size_t)c3 * 16 + lane];
        acc.x += (v0.x + v1.x) + (v2.x + v3.x);
        acc.y += (v0.y + v1.y) + (v2.y + v3.y);
        acc.z += (v0.z + v1.z) + (v2.z + v3.z);
        acc.w += (v0.w + v1.w) + (v2.w + v3.w);
    }
    for (; e < end; ++e) {
        int c = col[e];
        float4 v = xws[(size_t)c * 16 + lane];
        acc.x += v.x; acc.y += v.y; acc.z += v.z; acc.w += v.w;
    }
    float dv = dinv[node];
    const float4 b4 = *(const float4*)(bias + lane * 4);
    float4 o;
    o.x = fmaxf(fmaf(acc.x, dv, b4.x), 0.0f);
    o.y = fmaxf(fmaf(acc.y, dv, b4.y), 0.0f);
    o.z = fmaxf(fmaf(acc.z, dv, b4.z), 0.0f);
    o.w = fmaxf(fmaf(acc.w, dv, b4.w), 0.0f);
    out[(size_t)node * 16 + lane] = o;
}

// ---------------- pooling ----------------

__global__ void pool_zero(float* pooled, float* cnt, int G) {
    int idx = blockIdx.x * blockDim.x + threadIdx.x;
    if (idx < G * HDIM) pooled[idx] = 0.0f;
    if (idx < G) cnt[idx] = 0.0f;
}

__global__ void pool_accum(const float* __restrict__ h, const int* __restrict__ batch,
                           float* pooled, float* cnt, int n) {
    int idx = blockIdx.x * blockDim.x + threadIdx.x;
    if (idx >= n * 16) return;
    int i = idx >> 4, fo = (idx & 15) << 2;
    int g = batch[i];
    float4 v = *(const float4*)(h + (size_t)i * HDIM + fo);
    float* p = pooled + (size_t)g * HDIM + fo;
    atomicAdd(p + 0, v.x);
    atomicAdd(p + 1, v.y);
    atomicAdd(p + 2, v.z);
    atomicAdd(p + 3, v.w);
    if ((idx & 15) == 0) atomicAdd(cnt + g, 1.0f);
}

// ---------------- head: sigmoid(mean @ Wl + bl) ----------------

__global__ void final_head(const float* __restrict__ pooled, const float* __restrict__ cnt,
                           const float* __restrict__ Wl, const float* __restrict__ bl,
                           float* out, int G) {
    int g = blockIdx.x * (blockDim.x >> 6) + (threadIdx.x >> 6);
    int lane = threadIdx.x & 63;
    if (g >= G) return;
    float c = fmaxf(cnt[g], 1.0f);
    float v = pooled[(size_t)g * HDIM + lane] * (1.0f / c) * Wl[lane];
#pragma unroll
    for (int off = 32; off; off >>= 1) v += __shfl_down(v, off, 64);
    if (lane == 0) out[g] = 1.0f / (1.0f + expf(-(v + bl[0])));
}

// ---------------- launch ----------------

extern "C" void kernel_launch(void* const* d_in, const int* in_sizes, int n_in,
                              void* d_out, int out_size, void* d_ws, size_t ws_size,
                              hipStream_t stream) {
    const float* x   = (const float*)d_in[0];
    const int* ei    = (const int*)d_in[1];
    const int* batch = (const int*)d_in[2];
    const float* W1  = (const float*)d_in[3];
    const float* b1  = (const float*)d_in[4];
    const float* W2  = (const float*)d_in[5];
    const float* b2  = (const float*)d_in[6];
    const float* Wl  = (const float*)d_in[7];
    const float* bl  = (const float*)d_in[8];
    float* out = (float*)d_out;

    const int n = in_sizes[0] / F_IN;   // 100000
    const int E = in_sizes[1] / 2;      // 1600000
    const int G = out_size;             // 512

    const int* srcp = ei;
    const int* dstp = ei + E;

    // workspace layout
    char* wsb = (char*)d_ws;
    auto alloc = [&](size_t bytes) { char* p = wsb; wsb += (bytes + 255) & ~(size_t)255; return p; };
    int*   deg       = (int*)alloc((size_t)n * 4);
    int*   tmp_scan  = (int*)alloc((size_t)n * 4);
    int*   partials  = (int*)alloc(512 * 4);
    int*   row_start = (int*)alloc((size_t)n * 4);
    int*   cursor    = (int*)alloc((size_t)n * 4);
    float* dinv      = (float*)alloc((size_t)n * 4);
    int*   colx      = (int*)alloc((size_t)E * 4);
    float* bufA      = (float*)alloc((size_t)n * HDIM * 4);
    float* bufB      = (float*)alloc((size_t)n * HDIM * 4);
    float* pooled    = (float*)alloc((size_t)G * HDIM * 4);
    float* cnt       = (float*)alloc((size_t)G * 4);

    const int TB = 256;
    int gN   = (n + TB - 1) / TB;
    int gE   = (E + TB - 1) / TB;
    int gN16 = (n * 16 + TB - 1) / TB;
    int gMM  = (n + 7) / 8;
    int nb   = (n + SCAN_B - 1) / SCAN_B;   // scan blocks (391 <= 512)

    // CSR build + dinv
    zero_ints<<<gN, TB, 0, stream>>>(deg, n);
    count_deg<<<gE, TB, 0, stream>>>(dstp, deg, E);
    scan1<<<nb, SCAN_B, 0, stream>>>(deg, tmp_scan, partials, n);
    scan2<<<1, 512, 0, stream>>>(partials, nb);
    scan3<<<gN, TB, 0, stream>>>(deg, tmp_scan, partials, row_start, cursor, dinv, n);
    scatter_edges<<<gE, TB, 0, stream>>>(srcp, dstp, cursor, colx, E);

    // layer 1: xws = (x @ W1) * dinv ; h = relu(dinv * (xws_self + gather) + b1)
    matmul_scaled<F_IN><<<gMM, 512, 0, stream>>>(x, W1, dinv, bufA, n);
    csr_gather<<<gN16, TB, 0, stream>>>(colx, row_start, deg, dinv,
                                        (const float4*)bufA, b1, (float4*)bufB, n);

    // layer 2
    matmul_scaled<HDIM><<<gMM, 512, 0, stream>>>(bufB, W2, dinv, bufA, n);
    csr_gather<<<gN16, TB, 0, stream>>>(colx, row_start, deg, dinv,
                                        (const float4*)bufA, b2, (float4*)bufB, n);

    // pooling + head
    pool_zero<<<(G * HDIM + TB - 1) / TB, TB, 0, stream>>>(pooled, cnt, G);
    pool_accum<<<gN16, TB, 0, stream>>>(bufB, batch, pooled, cnt, n);
    final_head<<<(G + 3) / 4, TB, 0, stream>>>(pooled, cnt, Wl, bl, out, G);
}

// Round 3
// 568.731 us; speedup vs baseline: 5.8197x; 1.3484x over previous
//
#include <hip/hip_runtime.h>
#include <cmath>

#define F_IN 128
#define HDIM 64
#define SCAN_B 256   // elements per scan block

// ---------------- CSR build ----------------

__global__ void zero_ints(int* p, int n) {
    int i = blockIdx.x * blockDim.x + threadIdx.x;
    if (i < n) p[i] = 0;
}

__global__ void count_deg(const int* __restrict__ dst, int* deg, int E) {
    int e = blockIdx.x * blockDim.x + threadIdx.x;
    if (e < E) atomicAdd(deg + dst[e], 1);
}

// block-wise inclusive scan; writes scanned chunk + per-block total
__global__ void scan1(const int* __restrict__ deg, int* __restrict__ tmp,
                      int* __restrict__ partials, int n) {
    __shared__ int sd[SCAN_B];
    int tid = threadIdx.x;
    int i = blockIdx.x * SCAN_B + tid;
    int v = (i < n) ? deg[i] : 0;
    sd[tid] = v;
    __syncthreads();
    for (int off = 1; off < SCAN_B; off <<= 1) {
        int add = (tid >= off) ? sd[tid - off] : 0;
        __syncthreads();
        sd[tid] += add;
        __syncthreads();
    }
    if (i < n) tmp[i] = sd[tid];
    if (tid == SCAN_B - 1) partials[blockIdx.x] = sd[tid];
}

// single-block scan of partials (nb <= 512)
__global__ void scan2(int* partials, int nb) {
    __shared__ int sd[512];
    int tid = threadIdx.x;
    sd[tid] = (tid < nb) ? partials[tid] : 0;
    __syncthreads();
    for (int off = 1; off < 512; off <<= 1) {
        int add = (tid >= off) ? sd[tid - off] : 0;
        __syncthreads();
        sd[tid] += add;
        __syncthreads();
    }
    if (tid < nb) partials[tid] = sd[tid];
}

// finalize: exclusive row_start, cursor copy, dinv = rsqrt(deg+1)
__global__ void scan3(const int* __restrict__ deg, const int* __restrict__ tmp,
                      const int* __restrict__ partials, int* __restrict__ row_start,
                      int* __restrict__ cursor, float* __restrict__ dinv, int n) {
    int i = blockIdx.x * blockDim.x + threadIdx.x;
    if (i >= n) return;
    int b = i / SCAN_B;
    int excl = tmp[i] - deg[i] + (b > 0 ? partials[b - 1] : 0);
    row_start[i] = excl;
    cursor[i] = excl;
    dinv[i] = rsqrtf((float)(deg[i] + 1));
}

__global__ void scatter_edges(const int* __restrict__ src, const int* __restrict__ dst,
                              int* cursor, int* __restrict__ col, int E) {
    int e = blockIdx.x * blockDim.x + threadIdx.x;
    if (e >= E) return;
    int pos = atomicAdd(cursor + dst[e], 1);
    col[pos] = src[e];
}

// ---------------- graph segment boundaries (batch is sorted) ----------------
// gstart[g] = first index i with batch[i] >= g ; gstart[G] = n

__global__ void graph_bounds(const int* __restrict__ batch, int* __restrict__ gstart,
                             int n, int G) {
    int g = blockIdx.x * blockDim.x + threadIdx.x;
    if (g > G) return;
    int lo = 0, hi = n;
    while (lo < hi) {
        int mid = (lo + hi) >> 1;
        if (batch[mid] < g) lo = mid + 1; else hi = mid;
    }
    gstart[g] = lo;
}

// ---------------- dense matmul, epilogue scale by dinv[row] ----------------
// out[r, c] = (X @ W)[r, c] * dinv[r]

template <int K>
__launch_bounds__(512)
__global__ void matmul_scaled(const float* __restrict__ X, const float* __restrict__ W,
                              const float* __restrict__ dinv, float* __restrict__ out, int n) {
    __shared__ float Wl[K * HDIM];
    __shared__ float Xl[8 * K];
    int tid = threadIdx.x;
    for (int i = tid; i < K * HDIM; i += 512) Wl[i] = W[i];
    int base = blockIdx.x * 8;
    for (int i = tid; i < 8 * K; i += 512) {
        int gr = base + i / K;
        Xl[i] = (gr < n) ? X[(size_t)base * K + i] : 0.0f;
    }
    __syncthreads();
    int r = tid >> 6;       // 0..7
    int col = tid & 63;     // 0..63
    int row = base + r;
    if (row >= n) return;
    const float* xr = Xl + r * K;
    float acc = 0.0f;
#pragma unroll
    for (int k = 0; k < K; ++k) acc = fmaf(xr[k], Wl[k * HDIM + col], acc);
    out[(size_t)row * HDIM + col] = acc * dinv[row];
}

// ---------------- pull-mode aggregation ----------------
// out[i] = relu(dinv[i] * (xws[i] + sum_{e in row i} xws[col[e]]) + bias)
// 16 lanes per node, one float4 per lane.

__global__ void csr_gather(const int* __restrict__ col, const int* __restrict__ row_start,
                           const int* __restrict__ deg, const float* __restrict__ dinv,
                           const float4* __restrict__ xws, const float* __restrict__ bias,
                           float4* __restrict__ out, int n) {
    int t = blockIdx.x * blockDim.x + threadIdx.x;
    int node = t >> 4;
    if (node >= n) return;
    int lane = t & 15;
    int s = row_start[node];
    int end = s + deg[node];

    float4 acc = xws[(size_t)node * 16 + lane];   // self-loop term
    int e = s;
    for (; e + 4 <= end; e += 4) {
        int c0 = col[e], c1 = col[e + 1], c2 = col[e + 2], c3 = col[e + 3];
        float4 v0 = xws[(size_t)c0 * 16 + lane];
        float4 v1 = xws[(size_t)c1 * 16 + lane];
        float4 v2 = xws[(size_t)c2 * 16 + lane];
        float4 v3 = xws[(size_t)c3 * 16 + lane];
        acc.x += (v0.x + v1.x) + (v2.x + v3.x);
        acc.y += (v0.y + v1.y) + (v2.y + v3.y);
        acc.z += (v0.z + v1.z) + (v2.z + v3.z);
        acc.w += (v0.w + v1.w) + (v2.w + v3.w);
    }
    for (; e < end; ++e) {
        int c = col[e];
        float4 v = xws[(size_t)c * 16 + lane];
        acc.x += v.x; acc.y += v.y; acc.z += v.z; acc.w += v.w;
    }
    float dv = dinv[node];
    const float4 b4 = *(const float4*)(bias + lane * 4);
    float4 o;
    o.x = fmaxf(fmaf(acc.x, dv, b4.x), 0.0f);
    o.y = fmaxf(fmaf(acc.y, dv, b4.y), 0.0f);
    o.z = fmaxf(fmaf(acc.z, dv, b4.z), 0.0f);
    o.w = fmaxf(fmaf(acc.w, dv, b4.w), 0.0f);
    out[(size_t)node * 16 + lane] = o;
}

// ---------------- fused mean-pool + linear head + sigmoid ----------------
// one 256-thread block per graph; batch sorted -> contiguous segment [gstart[g], gstart[g+1])

__launch_bounds__(256)
__global__ void pool_head(const float* __restrict__ h, const int* __restrict__ gstart,
                          const float* __restrict__ Wl, const float* __restrict__ bl,
                          float* __restrict__ out, int G) {
    int g = blockIdx.x;
    int s = gstart[g], e = gstart[g + 1];
    int f  = threadIdx.x & 63;    // feature
    int rg = threadIdx.x >> 6;    // row group 0..3
    float acc = 0.0f;
    for (int i = s + rg; i < e; i += 4)
        acc += h[(size_t)i * HDIM + f];
    __shared__ float red[4][HDIM];
    red[rg][f] = acc;
    __syncthreads();
    if (rg == 0) {
        float v = (red[0][f] + red[1][f]) + (red[2][f] + red[3][f]);
        float c = fmaxf((float)(e - s), 1.0f);
        v = v * Wl[f] * (1.0f / c);
#pragma unroll
        for (int off = 32; off; off >>= 1) v += __shfl_down(v, off, 64);
        if (f == 0) out[g] = 1.0f / (1.0f + expf(-(v + bl[0])));
    }
}

// ---------------- launch ----------------

extern "C" void kernel_launch(void* const* d_in, const int* in_sizes, int n_in,
                              void* d_out, int out_size, void* d_ws, size_t ws_size,
                              hipStream_t stream) {
    const float* x   = (const float*)d_in[0];
    const int* ei    = (const int*)d_in[1];
    const int* batch = (const int*)d_in[2];
    const float* W1  = (const float*)d_in[3];
    const float* b1  = (const float*)d_in[4];
    const float* W2  = (const float*)d_in[5];
    const float* b2  = (const float*)d_in[6];
    const float* Wl  = (const float*)d_in[7];
    const float* bl  = (const float*)d_in[8];
    float* out = (float*)d_out;

    const int n = in_sizes[0] / F_IN;   // 100000
    const int E = in_sizes[1] / 2;      // 1600000
    const int G = out_size;             // 512

    const int* srcp = ei;
    const int* dstp = ei + E;

    // workspace layout
    char* wsb = (char*)d_ws;
    auto alloc = [&](size_t bytes) { char* p = wsb; wsb += (bytes + 255) & ~(size_t)255; return p; };
    int*   deg       = (int*)alloc((size_t)n * 4);
    int*   tmp_scan  = (int*)alloc((size_t)n * 4);
    int*   partials  = (int*)alloc(512 * 4);
    int*   row_start = (int*)alloc((size_t)n * 4);
    int*   cursor    = (int*)alloc((size_t)n * 4);
    float* dinv      = (float*)alloc((size_t)n * 4);
    int*   colx      = (int*)alloc((size_t)E * 4);
    float* bufA      = (float*)alloc((size_t)n * HDIM * 4);
    float* bufB      = (float*)alloc((size_t)n * HDIM * 4);
    int*   gstart    = (int*)alloc(((size_t)G + 1) * 4);

    const int TB = 256;
    int gN   = (n + TB - 1) / TB;
    int gE   = (E + TB - 1) / TB;
    int gN16 = (n * 16 + TB - 1) / TB;
    int gMM  = (n + 7) / 8;
    int nb   = (n + SCAN_B - 1) / SCAN_B;   // scan blocks (391 <= 512)

    // CSR build + dinv + graph bounds
    zero_ints<<<gN, TB, 0, stream>>>(deg, n);
    count_deg<<<gE, TB, 0, stream>>>(dstp, deg, E);
    scan1<<<nb, SCAN_B, 0, stream>>>(deg, tmp_scan, partials, n);
    scan2<<<1, 512, 0, stream>>>(partials, nb);
    scan3<<<gN, TB, 0, stream>>>(deg, tmp_scan, partials, row_start, cursor, dinv, n);
    scatter_edges<<<gE, TB, 0, stream>>>(srcp, dstp, cursor, colx, E);
    graph_bounds<<<(G + 1 + TB - 1) / TB, TB, 0, stream>>>(batch, gstart, n, G);

    // layer 1: xws = (x @ W1) * dinv ; h = relu(dinv * (xws_self + gather) + b1)
    matmul_scaled<F_IN><<<gMM, 512, 0, stream>>>(x, W1, dinv, bufA, n);
    csr_gather<<<gN16, TB, 0, stream>>>(colx, row_start, deg, dinv,
                                        (const float4*)bufA, b1, (float4*)bufB, n);

    // layer 2
    matmul_scaled<HDIM><<<gMM, 512, 0, stream>>>(bufB, W2, dinv, bufA, n);
    csr_gather<<<gN16, TB, 0, stream>>>(colx, row_start, deg, dinv,
                                        (const float4*)bufA, b2, (float4*)bufB, n);

    // fused pooling + head
    pool_head<<<G, 256, 0, stream>>>(bufB, gstart, Wl, bl, out, G);
}

// Round 4
// 479.420 us; speedup vs baseline: 6.9039x; 1.1863x over previous
//
#include <hip/hip_runtime.h>
#include <hip/hip_bf16.h>
#include <cmath>

#define F_IN 128
#define HDIM 64
#define SCAN_B 256   // elements per scan block

__device__ __forceinline__ float bf2f(unsigned short u) {
    union { unsigned int i; float f; } v; v.i = ((unsigned int)u) << 16; return v.f;
}

// ---------------- CSR build ----------------

__global__ void zero_ints(int* p, int n) {
    int i = blockIdx.x * blockDim.x + threadIdx.x;
    if (i < n) p[i] = 0;
}

__global__ void count_deg(const int* __restrict__ dst, int* deg, int E) {
    int e = blockIdx.x * blockDim.x + threadIdx.x;
    if (e < E) atomicAdd(deg + dst[e], 1);
}

// block-wise inclusive scan; writes scanned chunk + per-block total
__global__ void scan1(const int* __restrict__ deg, int* __restrict__ tmp,
                      int* __restrict__ partials, int n) {
    __shared__ int sd[SCAN_B];
    int tid = threadIdx.x;
    int i = blockIdx.x * SCAN_B + tid;
    int v = (i < n) ? deg[i] : 0;
    sd[tid] = v;
    __syncthreads();
    for (int off = 1; off < SCAN_B; off <<= 1) {
        int add = (tid >= off) ? sd[tid - off] : 0;
        __syncthreads();
        sd[tid] += add;
        __syncthreads();
    }
    if (i < n) tmp[i] = sd[tid];
    if (tid == SCAN_B - 1) partials[blockIdx.x] = sd[tid];
}

// single-block scan of partials (nb <= 512)
__global__ void scan2(int* partials, int nb) {
    __shared__ int sd[512];
    int tid = threadIdx.x;
    sd[tid] = (tid < nb) ? partials[tid] : 0;
    __syncthreads();
    for (int off = 1; off < 512; off <<= 1) {
        int add = (tid >= off) ? sd[tid - off] : 0;
        __syncthreads();
        sd[tid] += add;
        __syncthreads();
    }
    if (tid < nb) partials[tid] = sd[tid];
}

// finalize: exclusive row_start, cursor copy, dinv = rsqrt(deg+1)
__global__ void scan3(const int* __restrict__ deg, const int* __restrict__ tmp,
                      const int* __restrict__ partials, int* __restrict__ row_start,
                      int* __restrict__ cursor, float* __restrict__ dinv, int n) {
    int i = blockIdx.x * blockDim.x + threadIdx.x;
    if (i >= n) return;
    int b = i / SCAN_B;
    int excl = tmp[i] - deg[i] + (b > 0 ? partials[b - 1] : 0);
    row_start[i] = excl;
    cursor[i] = excl;
    dinv[i] = rsqrtf((float)(deg[i] + 1));
}

// XCD-partitioned scatter: part p = blockIdx%8 handles node range
// [p*npp, (p+1)*npp). Every part scans all dst (coalesced, L3-resident);
// col-region writes for one part stay on one XCD's L2 -> lines merge.
__global__ void scatter_edges_xcd(const int* __restrict__ src, const int* __restrict__ dst,
                                  int* cursor, int* __restrict__ col, int E, int npp) {
    int part = blockIdx.x & 7;
    int nb   = gridDim.x >> 3;
    int bi   = blockIdx.x >> 3;
    int lo   = part * npp;
    for (int e = bi * blockDim.x + threadIdx.x; e < E; e += nb * blockDim.x) {
        int d = dst[e];
        if ((unsigned)(d - lo) < (unsigned)npp) {
            int pos = atomicAdd(cursor + d, 1);
            col[pos] = src[e];
        }
    }
}

// ---------------- graph segment boundaries (batch is sorted) ----------------

__global__ void graph_bounds(const int* __restrict__ batch, int* __restrict__ gstart,
                             int n, int G) {
    int g = blockIdx.x * blockDim.x + threadIdx.x;
    if (g > G) return;
    int lo = 0, hi = n;
    while (lo < hi) {
        int mid = (lo + hi) >> 1;
        if (batch[mid] < g) lo = mid + 1; else hi = mid;
    }
    gstart[g] = lo;
}

// ---------------- dense matmul, epilogue scale by dinv[row], bf16 out ----------------

template <int K>
__launch_bounds__(512)
__global__ void matmul_scaled(const float* __restrict__ X, const float* __restrict__ W,
                              const float* __restrict__ dinv, __hip_bfloat16* __restrict__ out,
                              int n) {
    __shared__ float Wl[K * HDIM];
    __shared__ float Xl[8 * K];
    int tid = threadIdx.x;
    for (int i = tid; i < K * HDIM; i += 512) Wl[i] = W[i];
    int base = blockIdx.x * 8;
    for (int i = tid; i < 8 * K; i += 512) {
        int gr = base + i / K;
        Xl[i] = (gr < n) ? X[(size_t)base * K + i] : 0.0f;
    }
    __syncthreads();
    int r = tid >> 6;       // 0..7
    int col = tid & 63;     // 0..63
    int row = base + r;
    if (row >= n) return;
    const float* xr = Xl + r * K;
    float acc = 0.0f;
#pragma unroll
    for (int k = 0; k < K; ++k) acc = fmaf(xr[k], Wl[k * HDIM + col], acc);
    out[(size_t)row * HDIM + col] = __float2bfloat16(acc * dinv[row]);
}

// ---------------- pull-mode aggregation (bf16 rows, f32 accumulate) ----------------
// out[i] = relu(dinv[i] * (xws[i] + sum_{e in row i} xws[col[e]]) + bias)
// 16 lanes per node; lane owns 4 features (8 B of the 128 B bf16 row).

__global__ void csr_gather(const int* __restrict__ col, const int* __restrict__ row_start,
                           const int* __restrict__ deg, const float* __restrict__ dinv,
                           const ushort4* __restrict__ xws, const float* __restrict__ bias,
                           float4* __restrict__ out, int n) {
    int t = blockIdx.x * blockDim.x + threadIdx.x;
    int node = t >> 4;
    if (node >= n) return;
    int lane = t & 15;
    int s = row_start[node];
    int end = s + deg[node];

    ushort4 sv = xws[(size_t)node * 16 + lane];   // self-loop term
    float4 acc = { bf2f(sv.x), bf2f(sv.y), bf2f(sv.z), bf2f(sv.w) };
    int e = s;
    for (; e + 4 <= end; e += 4) {
        int c0 = col[e], c1 = col[e + 1], c2 = col[e + 2], c3 = col[e + 3];
        ushort4 v0 = xws[(size_t)c0 * 16 + lane];
        ushort4 v1 = xws[(size_t)c1 * 16 + lane];
        ushort4 v2 = xws[(size_t)c2 * 16 + lane];
        ushort4 v3 = xws[(size_t)c3 * 16 + lane];
        acc.x += (bf2f(v0.x) + bf2f(v1.x)) + (bf2f(v2.x) + bf2f(v3.x));
        acc.y += (bf2f(v0.y) + bf2f(v1.y)) + (bf2f(v2.y) + bf2f(v3.y));
        acc.z += (bf2f(v0.z) + bf2f(v1.z)) + (bf2f(v2.z) + bf2f(v3.z));
        acc.w += (bf2f(v0.w) + bf2f(v1.w)) + (bf2f(v2.w) + bf2f(v3.w));
    }
    for (; e < end; ++e) {
        int c = col[e];
        ushort4 v = xws[(size_t)c * 16 + lane];
        acc.x += bf2f(v.x); acc.y += bf2f(v.y); acc.z += bf2f(v.z); acc.w += bf2f(v.w);
    }
    float dv = dinv[node];
    const float4 b4 = *(const float4*)(bias + lane * 4);
    float4 o;
    o.x = fmaxf(fmaf(acc.x, dv, b4.x), 0.0f);
    o.y = fmaxf(fmaf(acc.y, dv, b4.y), 0.0f);
    o.z = fmaxf(fmaf(acc.z, dv, b4.z), 0.0f);
    o.w = fmaxf(fmaf(acc.w, dv, b4.w), 0.0f);
    out[(size_t)node * 16 + lane] = o;
}

// ---------------- fused mean-pool + linear head + sigmoid ----------------

__launch_bounds__(256)
__global__ void pool_head(const float* __restrict__ h, const int* __restrict__ gstart,
                          const float* __restrict__ Wl, const float* __restrict__ bl,
                          float* __restrict__ out, int G) {
    int g = blockIdx.x;
    int s = gstart[g], e = gstart[g + 1];
    int f  = threadIdx.x & 63;    // feature
    int rg = threadIdx.x >> 6;    // row group 0..3
    float acc = 0.0f;
    for (int i = s + rg; i < e; i += 4)
        acc += h[(size_t)i * HDIM + f];
    __shared__ float red[4][HDIM];
    red[rg][f] = acc;
    __syncthreads();
    if (rg == 0) {
        float v = (red[0][f] + red[1][f]) + (red[2][f] + red[3][f]);
        float c = fmaxf((float)(e - s), 1.0f);
        v = v * Wl[f] * (1.0f / c);
#pragma unroll
        for (int off = 32; off; off >>= 1) v += __shfl_down(v, off, 64);
        if (f == 0) out[g] = 1.0f / (1.0f + expf(-(v + bl[0])));
    }
}

// ---------------- launch ----------------

extern "C" void kernel_launch(void* const* d_in, const int* in_sizes, int n_in,
                              void* d_out, int out_size, void* d_ws, size_t ws_size,
                              hipStream_t stream) {
    const float* x   = (const float*)d_in[0];
    const int* ei    = (const int*)d_in[1];
    const int* batch = (const int*)d_in[2];
    const float* W1  = (const float*)d_in[3];
    const float* b1  = (const float*)d_in[4];
    const float* W2  = (const float*)d_in[5];
    const float* b2  = (const float*)d_in[6];
    const float* Wl  = (const float*)d_in[7];
    const float* bl  = (const float*)d_in[8];
    float* out = (float*)d_out;

    const int n = in_sizes[0] / F_IN;   // 100000
    const int E = in_sizes[1] / 2;      // 1600000
    const int G = out_size;             // 512

    const int* srcp = ei;
    const int* dstp = ei + E;

    // workspace layout
    char* wsb = (char*)d_ws;
    auto alloc = [&](size_t bytes) { char* p = wsb; wsb += (bytes + 255) & ~(size_t)255; return p; };
    int*   deg       = (int*)alloc((size_t)n * 4);
    int*   tmp_scan  = (int*)alloc((size_t)n * 4);
    int*   partials  = (int*)alloc(512 * 4);
    int*   row_start = (int*)alloc((size_t)n * 4);
    int*   cursor    = (int*)alloc((size_t)n * 4);
    float* dinv      = (float*)alloc((size_t)n * 4);
    int*   colx      = (int*)alloc((size_t)E * 4);
    __hip_bfloat16* xwsb = (__hip_bfloat16*)alloc((size_t)n * HDIM * 2);
    float* bufB      = (float*)alloc((size_t)n * HDIM * 4);
    int*   gstart    = (int*)alloc(((size_t)G + 1) * 4);

    const int TB = 256;
    int gN   = (n + TB - 1) / TB;
    int gE   = (E + TB - 1) / TB;
    int gN16 = (n * 16 + TB - 1) / TB;
    int gMM  = (n + 7) / 8;
    int nb   = (n + SCAN_B - 1) / SCAN_B;   // 391 <= 512
    int npp  = (n + 7) / 8;                 // nodes per XCD partition

    // CSR build + dinv + graph bounds
    zero_ints<<<gN, TB, 0, stream>>>(deg, n);
    count_deg<<<gE, TB, 0, stream>>>(dstp, deg, E);
    scan1<<<nb, SCAN_B, 0, stream>>>(deg, tmp_scan, partials, n);
    scan2<<<1, 512, 0, stream>>>(partials, nb);
    scan3<<<gN, TB, 0, stream>>>(deg, tmp_scan, partials, row_start, cursor, dinv, n);
    scatter_edges_xcd<<<1024, TB, 0, stream>>>(srcp, dstp, cursor, colx, E, npp);
    graph_bounds<<<(G + 1 + TB - 1) / TB, TB, 0, stream>>>(batch, gstart, n, G);

    // layer 1
    matmul_scaled<F_IN><<<gMM, 512, 0, stream>>>(x, W1, dinv, xwsb, n);
    csr_gather<<<gN16, TB, 0, stream>>>(colx, row_start, deg, dinv,
                                        (const ushort4*)xwsb, b1, (float4*)bufB, n);

    // layer 2
    matmul_scaled<HDIM><<<gMM, 512, 0, stream>>>(bufB, W2, dinv, xwsb, n);
    csr_gather<<<gN16, TB, 0, stream>>>(colx, row_start, deg, dinv,
                                        (const ushort4*)xwsb, b2, (float4*)bufB, n);

    // fused pooling + head
    pool_head<<<G, 256, 0, stream>>>(bufB, gstart, Wl, bl, out, G);
}

// Round 5
// 372.598 us; speedup vs baseline: 8.8832x; 1.2867x over previous
//
#include <hip/hip_runtime.h>
#include <hip/hip_bf16.h>
#include <cmath>

#define F_IN 128
#define HDIM 64
#define SCAN_B 256   // elements per scan block

typedef __attribute__((ext_vector_type(8))) short bf16x8;
typedef __attribute__((ext_vector_type(4))) float f32x4;

__device__ __forceinline__ float bf2f(unsigned short u) {
    union { unsigned int i; float f; } v; v.i = ((unsigned int)u) << 16; return v.f;
}
__device__ __forceinline__ unsigned short f2bf(float f) {
    __hip_bfloat16 h = __float2bfloat16(f);
    union { __hip_bfloat16 h; unsigned short u; } c; c.h = h; return c.u;
}

// ---------------- CSR build ----------------

__global__ void zero_ints(int* p, int n) {
    int i = blockIdx.x * blockDim.x + threadIdx.x;
    if (i < n) p[i] = 0;
}

__global__ void count_deg(const int* __restrict__ dst, int* deg, int E) {
    int e = blockIdx.x * blockDim.x + threadIdx.x;
    if (e < E) atomicAdd(deg + dst[e], 1);
}

__global__ void scan1(const int* __restrict__ deg, int* __restrict__ tmp,
                      int* __restrict__ partials, int n) {
    __shared__ int sd[SCAN_B];
    int tid = threadIdx.x;
    int i = blockIdx.x * SCAN_B + tid;
    int v = (i < n) ? deg[i] : 0;
    sd[tid] = v;
    __syncthreads();
    for (int off = 1; off < SCAN_B; off <<= 1) {
        int add = (tid >= off) ? sd[tid - off] : 0;
        __syncthreads();
        sd[tid] += add;
        __syncthreads();
    }
    if (i < n) tmp[i] = sd[tid];
    if (tid == SCAN_B - 1) partials[blockIdx.x] = sd[tid];
}

__global__ void scan2(int* partials, int nb) {
    __shared__ int sd[512];
    int tid = threadIdx.x;
    sd[tid] = (tid < nb) ? partials[tid] : 0;
    __syncthreads();
    for (int off = 1; off < 512; off <<= 1) {
        int add = (tid >= off) ? sd[tid - off] : 0;
        __syncthreads();
        sd[tid] += add;
        __syncthreads();
    }
    if (tid < nb) partials[tid] = sd[tid];
}

__global__ void scan3(const int* __restrict__ deg, const int* __restrict__ tmp,
                      const int* __restrict__ partials, int* __restrict__ row_start,
                      int* __restrict__ cursor, float* __restrict__ dinv, int n) {
    int i = blockIdx.x * blockDim.x + threadIdx.x;
    if (i >= n) return;
    int b = i / SCAN_B;
    int excl = tmp[i] - deg[i] + (b > 0 ? partials[b - 1] : 0);
    row_start[i] = excl;
    cursor[i] = excl;
    dinv[i] = rsqrtf((float)(deg[i] + 1));
}

// XCD-partitioned scatter (see R3): col-region writes stay on one XCD's L2.
__global__ void scatter_edges_xcd(const int* __restrict__ src, const int* __restrict__ dst,
                                  int* cursor, int* __restrict__ col, int E, int npp) {
    int part = blockIdx.x & 7;
    int nb   = gridDim.x >> 3;
    int bi   = blockIdx.x >> 3;
    int lo   = part * npp;
    for (int e = bi * blockDim.x + threadIdx.x; e < E; e += nb * blockDim.x) {
        int d = dst[e];
        if ((unsigned)(d - lo) < (unsigned)npp) {
            int pos = atomicAdd(cursor + d, 1);
            col[pos] = src[e];
        }
    }
}

// ---------------- graph segment boundaries (batch is sorted) ----------------

__global__ void graph_bounds(const int* __restrict__ batch, int* __restrict__ gstart,
                             int n, int G) {
    int g = blockIdx.x * blockDim.x + threadIdx.x;
    if (g > G) return;
    int lo = 0, hi = n;
    while (lo < hi) {
        int mid = (lo + hi) >> 1;
        if (batch[mid] < g) lo = mid + 1; else hi = mid;
    }
    gstart[g] = lo;
}

// ---------------- MFMA matmul: out[r,c] = bf16((X@W)[r,c] * dinv[r]) ----------------
// 256 threads = 4 waves; block handles 64 rows; wave w handles rows w*16..w*16+15.
// X-tile staged to LDS as bf16 with +8 elem row pad (2-way bank alias = free).
// W staged to LDS as bf16; B-fragments hoisted to registers (loop-invariant).

template <int K>
__launch_bounds__(256)
__global__ void matmul_mfma(const float* __restrict__ X, const float* __restrict__ W,
                            const float* __restrict__ dinv, unsigned short* __restrict__ out,
                            int n) {
    constexpr int KS  = K / 32;    // MFMA k-steps
    constexpr int LDX = K + 8;     // padded LDS row stride (bf16 elems)
    __shared__ unsigned short Xs[64 * LDX];
    __shared__ unsigned short Wss[K * HDIM];

    int tid = threadIdx.x;
    int rowbase = blockIdx.x * 64;

    // stage W: f32 -> bf16 (row-major [K][64], contiguous)
    {
        const float4* W4 = (const float4*)W;
        for (int i = tid; i < K * HDIM / 4; i += 256) {
            float4 v = W4[i];
            ushort4 u = { f2bf(v.x), f2bf(v.y), f2bf(v.z), f2bf(v.w) };
            *(ushort4*)(Wss + i * 4) = u;
        }
    }
    // stage X tile: 64 rows x K, f32 -> bf16, zero-fill OOB rows
    {
        const float4* X4 = (const float4*)X;
        for (int i = tid; i < 64 * K / 4; i += 256) {
            int r = i / (K / 4), k4 = i % (K / 4);
            ushort4 u = { 0, 0, 0, 0 };
            int gr = rowbase + r;
            if (gr < n) {
                float4 v = X4[(size_t)gr * (K / 4) + k4];
                u.x = f2bf(v.x); u.y = f2bf(v.y); u.z = f2bf(v.z); u.w = f2bf(v.w);
            }
            *(ushort4*)(Xs + r * LDX + k4 * 4) = u;
        }
    }
    __syncthreads();

    int wave = tid >> 6, lane = tid & 63;
    int q = lane >> 4, nn = lane & 15;

    // B fragments: b[s][c][j] = W[s*32 + q*8 + j][c*16 + nn]
    bf16x8 bfrag[KS][4];
#pragma unroll
    for (int s = 0; s < KS; ++s)
#pragma unroll
        for (int c = 0; c < 4; ++c) {
            short tmp[8];
#pragma unroll
            for (int j = 0; j < 8; ++j)
                tmp[j] = (short)Wss[(s * 32 + q * 8 + j) * HDIM + c * 16 + nn];
            bfrag[s][c] = *(bf16x8*)tmp;
        }

    f32x4 acc[4] = {{0,0,0,0},{0,0,0,0},{0,0,0,0},{0,0,0,0}};
    int mrow = wave * 16 + nn;   // A row within tile (m = lane&15)
#pragma unroll
    for (int s = 0; s < KS; ++s) {
        bf16x8 af = *(const bf16x8*)(Xs + mrow * LDX + s * 32 + q * 8);
#pragma unroll
        for (int c = 0; c < 4; ++c)
            acc[c] = __builtin_amdgcn_mfma_f32_16x16x32_bf16(af, bfrag[s][c], acc[c], 0, 0, 0);
    }

    // D layout: row = q*4 + r (relative), col = c*16 + nn
#pragma unroll
    for (int r = 0; r < 4; ++r) {
        int row = rowbase + wave * 16 + q * 4 + r;
        if (row >= n) continue;
        float dv = dinv[row];
#pragma unroll
        for (int c = 0; c < 4; ++c)
            out[(size_t)row * HDIM + c * 16 + nn] = f2bf(acc[c][r] * dv);
    }
}

// ---------------- pull-mode aggregation (bf16 rows, f32 accumulate) ----------------

__global__ void csr_gather(const int* __restrict__ col, const int* __restrict__ row_start,
                           const int* __restrict__ deg, const float* __restrict__ dinv,
                           const ushort4* __restrict__ xws, const float* __restrict__ bias,
                           float4* __restrict__ out, int n) {
    int t = blockIdx.x * blockDim.x + threadIdx.x;
    int node = t >> 4;
    if (node >= n) return;
    int lane = t & 15;
    int s = row_start[node];
    int end = s + deg[node];

    ushort4 sv = xws[(size_t)node * 16 + lane];   // self-loop term
    float4 acc = { bf2f(sv.x), bf2f(sv.y), bf2f(sv.z), bf2f(sv.w) };
    int e = s;
    for (; e + 4 <= end; e += 4) {
        int c0 = col[e], c1 = col[e + 1], c2 = col[e + 2], c3 = col[e + 3];
        ushort4 v0 = xws[(size_t)c0 * 16 + lane];
        ushort4 v1 = xws[(size_t)c1 * 16 + lane];
        ushort4 v2 = xws[(size_t)c2 * 16 + lane];
        ushort4 v3 = xws[(size_t)c3 * 16 + lane];
        acc.x += (bf2f(v0.x) + bf2f(v1.x)) + (bf2f(v2.x) + bf2f(v3.x));
        acc.y += (bf2f(v0.y) + bf2f(v1.y)) + (bf2f(v2.y) + bf2f(v3.y));
        acc.z += (bf2f(v0.z) + bf2f(v1.z)) + (bf2f(v2.z) + bf2f(v3.z));
        acc.w += (bf2f(v0.w) + bf2f(v1.w)) + (bf2f(v2.w) + bf2f(v3.w));
    }
    for (; e < end; ++e) {
        int c = col[e];
        ushort4 v = xws[(size_t)c * 16 + lane];
        acc.x += bf2f(v.x); acc.y += bf2f(v.y); acc.z += bf2f(v.z); acc.w += bf2f(v.w);
    }
    float dv = dinv[node];
    const float4 b4 = *(const float4*)(bias + lane * 4);
    float4 o;
    o.x = fmaxf(fmaf(acc.x, dv, b4.x), 0.0f);
    o.y = fmaxf(fmaf(acc.y, dv, b4.y), 0.0f);
    o.z = fmaxf(fmaf(acc.z, dv, b4.z), 0.0f);
    o.w = fmaxf(fmaf(acc.w, dv, b4.w), 0.0f);
    out[(size_t)node * 16 + lane] = o;
}

// ---------------- fused mean-pool + linear head + sigmoid ----------------

__launch_bounds__(256)
__global__ void pool_head(const float* __restrict__ h, const int* __restrict__ gstart,
                          const float* __restrict__ Wl, const float* __restrict__ bl,
                          float* __restrict__ out, int G) {
    int g = blockIdx.x;
    int s = gstart[g], e = gstart[g + 1];
    int f  = threadIdx.x & 63;    // feature
    int rg = threadIdx.x >> 6;    // row group 0..3
    float acc = 0.0f;
    for (int i = s + rg; i < e; i += 4)
        acc += h[(size_t)i * HDIM + f];
    __shared__ float red[4][HDIM];
    red[rg][f] = acc;
    __syncthreads();
    if (rg == 0) {
        float v = (red[0][f] + red[1][f]) + (red[2][f] + red[3][f]);
        float c = fmaxf((float)(e - s), 1.0f);
        v = v * Wl[f] * (1.0f / c);
#pragma unroll
        for (int off = 32; off; off >>= 1) v += __shfl_down(v, off, 64);
        if (f == 0) out[g] = 1.0f / (1.0f + expf(-(v + bl[0])));
    }
}

// ---------------- launch ----------------

extern "C" void kernel_launch(void* const* d_in, const int* in_sizes, int n_in,
                              void* d_out, int out_size, void* d_ws, size_t ws_size,
                              hipStream_t stream) {
    const float* x   = (const float*)d_in[0];
    const int* ei    = (const int*)d_in[1];
    const int* batch = (const int*)d_in[2];
    const float* W1  = (const float*)d_in[3];
    const float* b1  = (const float*)d_in[4];
    const float* W2  = (const float*)d_in[5];
    const float* b2  = (const float*)d_in[6];
    const float* Wl  = (const float*)d_in[7];
    const float* bl  = (const float*)d_in[8];
    float* out = (float*)d_out;

    const int n = in_sizes[0] / F_IN;   // 100000
    const int E = in_sizes[1] / 2;      // 1600000
    const int G = out_size;             // 512

    const int* srcp = ei;
    const int* dstp = ei + E;

    // workspace layout
    char* wsb = (char*)d_ws;
    auto alloc = [&](size_t bytes) { char* p = wsb; wsb += (bytes + 255) & ~(size_t)255; return p; };
    int*   deg       = (int*)alloc((size_t)n * 4);
    int*   tmp_scan  = (int*)alloc((size_t)n * 4);
    int*   partials  = (int*)alloc(512 * 4);
    int*   row_start = (int*)alloc((size_t)n * 4);
    int*   cursor    = (int*)alloc((size_t)n * 4);
    float* dinv      = (float*)alloc((size_t)n * 4);
    int*   colx      = (int*)alloc((size_t)E * 4);
    unsigned short* xwsb = (unsigned short*)alloc((size_t)n * HDIM * 2);
    float* bufB      = (float*)alloc((size_t)n * HDIM * 4);
    int*   gstart    = (int*)alloc(((size_t)G + 1) * 4);

    const int TB = 256;
    int gN   = (n + TB - 1) / TB;
    int gE   = (E + TB - 1) / TB;
    int gN16 = (n * 16 + TB - 1) / TB;
    int gMM  = (n + 63) / 64;
    int nb   = (n + SCAN_B - 1) / SCAN_B;   // 391 <= 512
    int npp  = (n + 7) / 8;                 // nodes per XCD partition

    // CSR build + dinv + graph bounds
    zero_ints<<<gN, TB, 0, stream>>>(deg, n);
    count_deg<<<gE, TB, 0, stream>>>(dstp, deg, E);
    scan1<<<nb, SCAN_B, 0, stream>>>(deg, tmp_scan, partials, n);
    scan2<<<1, 512, 0, stream>>>(partials, nb);
    scan3<<<gN, TB, 0, stream>>>(deg, tmp_scan, partials, row_start, cursor, dinv, n);
    scatter_edges_xcd<<<1024, TB, 0, stream>>>(srcp, dstp, cursor, colx, E, npp);
    graph_bounds<<<(G + 1 + TB - 1) / TB, TB, 0, stream>>>(batch, gstart, n, G);

    // layer 1
    matmul_mfma<F_IN><<<gMM, 256, 0, stream>>>(x, W1, dinv, xwsb, n);
    csr_gather<<<gN16, TB, 0, stream>>>(colx, row_start, deg, dinv,
                                        (const ushort4*)xwsb, b1, (float4*)bufB, n);

    // layer 2
    matmul_mfma<HDIM><<<gMM, 256, 0, stream>>>(bufB, W2, dinv, xwsb, n);
    csr_gather<<<gN16, TB, 0, stream>>>(colx, row_start, deg, dinv,
                                        (const ushort4*)xwsb, b2, (float4*)bufB, n);

    // fused pooling + head
    pool_head<<<G, 256, 0, stream>>>(bufB, gstart, Wl, bl, out, G);
}

// Round 6
// 308.348 us; speedup vs baseline: 10.7342x; 1.2084x over previous
//
#include <hip/hip_runtime.h>
#include <hip/hip_bf16.h>
#include <cmath>

#define F_IN 128
#define HDIM 64
#define NPB 256          // nodes per bucket (dst >> 8)

typedef __attribute__((ext_vector_type(8))) short bf16x8;
typedef __attribute__((ext_vector_type(4))) float f32x4;

__device__ __forceinline__ float bf2f(unsigned short u) {
    union { unsigned int i; float f; } v; v.i = ((unsigned int)u) << 16; return v.f;
}
__device__ __forceinline__ unsigned short f2bf(float f) {
    __hip_bfloat16 h = __float2bfloat16(f);
    union { __hip_bfloat16 h; unsigned short u; } c; c.h = h; return c.u;
}

// ---------------- bucketed CSR build ----------------
// bucket(d) = d >> 8 ; nbuk = ceil(n/256) = 391 <= 512

__global__ void zero_ints(int* p, int n) {
    int i = blockIdx.x * blockDim.x + threadIdx.x;
    if (i < n) p[i] = 0;
}

// P0: global bucket histogram (LDS-reduced; ~nbuk global atomics per block)
__launch_bounds__(256)
__global__ void p0_hist(const int* __restrict__ dst, int* __restrict__ bucket_cnt,
                        int E, int nbuk) {
    __shared__ int hist[512];
    for (int i = threadIdx.x; i < nbuk; i += 256) hist[i] = 0;
    __syncthreads();
    for (int e = blockIdx.x * 256 + threadIdx.x; e < E; e += gridDim.x * 256)
        atomicAdd(&hist[dst[e] >> 8], 1);
    __syncthreads();
    for (int i = threadIdx.x; i < nbuk; i += 256)
        if (hist[i]) atomicAdd(&bucket_cnt[i], hist[i]);
}

// P0b: exclusive scan of bucket counts -> base, cursor (nbuk <= 512)
__global__ void p0_scan(const int* __restrict__ cnt, int* __restrict__ base,
                        int* __restrict__ cursor, int nbuk) {
    __shared__ int sd[512];
    int tid = threadIdx.x;
    int v = (tid < nbuk) ? cnt[tid] : 0;
    sd[tid] = v;
    __syncthreads();
    for (int off = 1; off < 512; off <<= 1) {
        int a = (tid >= off) ? sd[tid - off] : 0;
        __syncthreads();
        sd[tid] += a;
        __syncthreads();
    }
    if (tid < nbuk) { base[tid] = sd[tid] - v; cursor[tid] = sd[tid] - v; }
    if (tid == nbuk - 1) base[nbuk] = sd[tid];   // == E
}

// P1: persistent blocks partition edges into bucket-grouped packed ints.
// pairs[pos] = (src << 8) | (dst & 255); block reserves one range per bucket.
__launch_bounds__(256)
__global__ void p1_bucket(const int* __restrict__ src, const int* __restrict__ dst,
                          int* bucket_cursor, int* __restrict__ pairs,
                          int E, int nbuk, int chunk) {
    __shared__ int hist[512];
    __shared__ int cur[512];
    int tid = threadIdx.x;
    int lo = blockIdx.x * chunk;
    int hi = min(E, lo + chunk);
    for (int i = tid; i < nbuk; i += 256) hist[i] = 0;
    __syncthreads();
    for (int e = lo + tid; e < hi; e += 256)
        atomicAdd(&hist[dst[e] >> 8], 1);
    __syncthreads();
    for (int i = tid; i < nbuk; i += 256) {
        int h = hist[i];
        cur[i] = h ? atomicAdd(&bucket_cursor[i], h) : 0;
    }
    __syncthreads();
    for (int e = lo + tid; e < hi; e += 256) {
        int d = dst[e];
        int pos = atomicAdd(&cur[d >> 8], 1);
        pairs[pos] = (src[e] << 8) | (d & 255);
    }
}

// P2: one WG per bucket -> local CSR with LDS-only atomics.
__launch_bounds__(256)
__global__ void p2_csr(const int* __restrict__ pairs, const int* __restrict__ base,
                       int* __restrict__ row_start, int* __restrict__ deg,
                       float* __restrict__ dinv, int* __restrict__ col, int n) {
    __shared__ int dl[256];
    __shared__ int sc[256];
    __shared__ int cur[256];
    int b = blockIdx.x, tid = threadIdx.x;
    int nlo = b << 8;
    int eb = base[b], ee = base[b + 1];
    dl[tid] = 0;
    __syncthreads();
    for (int e = eb + tid; e < ee; e += 256)
        atomicAdd(&dl[pairs[e] & 255], 1);
    __syncthreads();
    int d0 = dl[tid];
    sc[tid] = d0;
    __syncthreads();
    for (int off = 1; off < 256; off <<= 1) {
        int a = (tid >= off) ? sc[tid - off] : 0;
        __syncthreads();
        sc[tid] += a;
        __syncthreads();
    }
    int excl = sc[tid] - d0;
    int node = nlo + tid;
    if (node < n) {
        row_start[node] = eb + excl;
        deg[node] = d0;
        dinv[node] = rsqrtf((float)(d0 + 1));
    }
    cur[tid] = eb + excl;
    __syncthreads();
    for (int e = eb + tid; e < ee; e += 256) {
        unsigned int v = (unsigned int)pairs[e];
        int pos = atomicAdd(&cur[v & 255], 1);
        col[pos] = (int)(v >> 8);
    }
}

// ---------------- graph segment boundaries (batch is sorted) ----------------

__global__ void graph_bounds(const int* __restrict__ batch, int* __restrict__ gstart,
                             int n, int G) {
    int g = blockIdx.x * blockDim.x + threadIdx.x;
    if (g > G) return;
    int lo = 0, hi = n;
    while (lo < hi) {
        int mid = (lo + hi) >> 1;
        if (batch[mid] < g) lo = mid + 1; else hi = mid;
    }
    gstart[g] = lo;
}

// ---------------- MFMA matmul: out[r,c] = bf16((X@W)[r,c] * dinv[r]) ----------------

template <int K>
__launch_bounds__(256)
__global__ void matmul_mfma(const float* __restrict__ X, const float* __restrict__ W,
                            const float* __restrict__ dinv, unsigned short* __restrict__ out,
                            int n) {
    constexpr int KS  = K / 32;
    constexpr int LDX = K + 8;
    __shared__ unsigned short Xs[64 * LDX];
    __shared__ unsigned short Wss[K * HDIM];

    int tid = threadIdx.x;
    int rowbase = blockIdx.x * 64;

    {
        const float4* W4 = (const float4*)W;
        for (int i = tid; i < K * HDIM / 4; i += 256) {
            float4 v = W4[i];
            ushort4 u = { f2bf(v.x), f2bf(v.y), f2bf(v.z), f2bf(v.w) };
            *(ushort4*)(Wss + i * 4) = u;
        }
    }
    {
        const float4* X4 = (const float4*)X;
        for (int i = tid; i < 64 * K / 4; i += 256) {
            int r = i / (K / 4), k4 = i % (K / 4);
            ushort4 u = { 0, 0, 0, 0 };
            int gr = rowbase + r;
            if (gr < n) {
                float4 v = X4[(size_t)gr * (K / 4) + k4];
                u.x = f2bf(v.x); u.y = f2bf(v.y); u.z = f2bf(v.z); u.w = f2bf(v.w);
            }
            *(ushort4*)(Xs + r * LDX + k4 * 4) = u;
        }
    }
    __syncthreads();

    int wave = tid >> 6, lane = tid & 63;
    int q = lane >> 4, nn = lane & 15;

    bf16x8 bfrag[KS][4];
#pragma unroll
    for (int s = 0; s < KS; ++s)
#pragma unroll
        for (int c = 0; c < 4; ++c) {
            short tmp[8];
#pragma unroll
            for (int j = 0; j < 8; ++j)
                tmp[j] = (short)Wss[(s * 32 + q * 8 + j) * HDIM + c * 16 + nn];
            bfrag[s][c] = *(bf16x8*)tmp;
        }

    f32x4 acc[4] = {{0,0,0,0},{0,0,0,0},{0,0,0,0},{0,0,0,0}};
    int mrow = wave * 16 + nn;
#pragma unroll
    for (int s = 0; s < KS; ++s) {
        bf16x8 af = *(const bf16x8*)(Xs + mrow * LDX + s * 32 + q * 8);
#pragma unroll
        for (int c = 0; c < 4; ++c)
            acc[c] = __builtin_amdgcn_mfma_f32_16x16x32_bf16(af, bfrag[s][c], acc[c], 0, 0, 0);
    }

#pragma unroll
    for (int r = 0; r < 4; ++r) {
        int row = rowbase + wave * 16 + q * 4 + r;
        if (row >= n) continue;
        float dv = dinv[row];
#pragma unroll
        for (int c = 0; c < 4; ++c)
            out[(size_t)row * HDIM + c * 16 + nn] = f2bf(acc[c][r] * dv);
    }
}

// ---------------- pull-mode aggregation (bf16 rows, f32 accumulate) ----------------

__global__ void csr_gather(const int* __restrict__ col, const int* __restrict__ row_start,
                           const int* __restrict__ deg, const float* __restrict__ dinv,
                           const ushort4* __restrict__ xws, const float* __restrict__ bias,
                           float4* __restrict__ out, int n) {
    int t = blockIdx.x * blockDim.x + threadIdx.x;
    int node = t >> 4;
    if (node >= n) return;
    int lane = t & 15;
    int s = row_start[node];
    int end = s + deg[node];

    ushort4 sv = xws[(size_t)node * 16 + lane];
    float4 acc = { bf2f(sv.x), bf2f(sv.y), bf2f(sv.z), bf2f(sv.w) };
    int e = s;
    for (; e + 4 <= end; e += 4) {
        int c0 = col[e], c1 = col[e + 1], c2 = col[e + 2], c3 = col[e + 3];
        ushort4 v0 = xws[(size_t)c0 * 16 + lane];
        ushort4 v1 = xws[(size_t)c1 * 16 + lane];
        ushort4 v2 = xws[(size_t)c2 * 16 + lane];
        ushort4 v3 = xws[(size_t)c3 * 16 + lane];
        acc.x += (bf2f(v0.x) + bf2f(v1.x)) + (bf2f(v2.x) + bf2f(v3.x));
        acc.y += (bf2f(v0.y) + bf2f(v1.y)) + (bf2f(v2.y) + bf2f(v3.y));
        acc.z += (bf2f(v0.z) + bf2f(v1.z)) + (bf2f(v2.z) + bf2f(v3.z));
        acc.w += (bf2f(v0.w) + bf2f(v1.w)) + (bf2f(v2.w) + bf2f(v3.w));
    }
    for (; e < end; ++e) {
        int c = col[e];
        ushort4 v = xws[(size_t)c * 16 + lane];
        acc.x += bf2f(v.x); acc.y += bf2f(v.y); acc.z += bf2f(v.z); acc.w += bf2f(v.w);
    }
    float dv = dinv[node];
    const float4 b4 = *(const float4*)(bias + lane * 4);
    float4 o;
    o.x = fmaxf(fmaf(acc.x, dv, b4.x), 0.0f);
    o.y = fmaxf(fmaf(acc.y, dv, b4.y), 0.0f);
    o.z = fmaxf(fmaf(acc.z, dv, b4.z), 0.0f);
    o.w = fmaxf(fmaf(acc.w, dv, b4.w), 0.0f);
    out[(size_t)node * 16 + lane] = o;
}

// ---------------- fused mean-pool + linear head + sigmoid ----------------

__launch_bounds__(256)
__global__ void pool_head(const float* __restrict__ h, const int* __restrict__ gstart,
                          const float* __restrict__ Wl, const float* __restrict__ bl,
                          float* __restrict__ out, int G) {
    int g = blockIdx.x;
    int s = gstart[g], e = gstart[g + 1];
    int f  = threadIdx.x & 63;
    int rg = threadIdx.x >> 6;
    float acc = 0.0f;
    for (int i = s + rg; i < e; i += 4)
        acc += h[(size_t)i * HDIM + f];
    __shared__ float red[4][HDIM];
    red[rg][f] = acc;
    __syncthreads();
    if (rg == 0) {
        float v = (red[0][f] + red[1][f]) + (red[2][f] + red[3][f]);
        float c = fmaxf((float)(e - s), 1.0f);
        v = v * Wl[f] * (1.0f / c);
#pragma unroll
        for (int off = 32; off; off >>= 1) v += __shfl_down(v, off, 64);
        if (f == 0) out[g] = 1.0f / (1.0f + expf(-(v + bl[0])));
    }
}

// ---------------- launch ----------------

extern "C" void kernel_launch(void* const* d_in, const int* in_sizes, int n_in,
                              void* d_out, int out_size, void* d_ws, size_t ws_size,
                              hipStream_t stream) {
    const float* x   = (const float*)d_in[0];
    const int* ei    = (const int*)d_in[1];
    const int* batch = (const int*)d_in[2];
    const float* W1  = (const float*)d_in[3];
    const float* b1  = (const float*)d_in[4];
    const float* W2  = (const float*)d_in[5];
    const float* b2  = (const float*)d_in[6];
    const float* Wl  = (const float*)d_in[7];
    const float* bl  = (const float*)d_in[8];
    float* out = (float*)d_out;

    const int n = in_sizes[0] / F_IN;   // 100000
    const int E = in_sizes[1] / 2;      // 1600000
    const int G = out_size;             // 512

    const int* srcp = ei;
    const int* dstp = ei + E;

    int nbuk = (n + NPB - 1) / NPB;     // 391 (<= 512)

    // workspace layout
    char* wsb = (char*)d_ws;
    auto alloc = [&](size_t bytes) { char* p = wsb; wsb += (bytes + 255) & ~(size_t)255; return p; };
    int*   deg        = (int*)alloc((size_t)n * 4);
    int*   row_start  = (int*)alloc((size_t)n * 4);
    float* dinv       = (float*)alloc((size_t)n * 4);
    int*   bucket_cnt = (int*)alloc(512 * 4);
    int*   bucket_base= (int*)alloc(513 * 4);
    int*   bucket_cur = (int*)alloc(512 * 4);
    int*   pairs      = (int*)alloc((size_t)E * 4);
    int*   colx       = (int*)alloc((size_t)E * 4);
    unsigned short* xwsb = (unsigned short*)alloc((size_t)n * HDIM * 2);
    float* bufB       = (float*)alloc((size_t)n * HDIM * 4);
    int*   gstart     = (int*)alloc(((size_t)G + 1) * 4);

    const int TB = 256;
    int gN16 = (n * 16 + TB - 1) / TB;
    int gMM  = (n + 63) / 64;
    const int NP1 = 128;
    int chunk = (E + NP1 - 1) / NP1;

    // bucketed CSR build
    zero_ints<<<(nbuk + TB - 1) / TB, TB, 0, stream>>>(bucket_cnt, nbuk);
    p0_hist<<<NP1, TB, 0, stream>>>(dstp, bucket_cnt, E, nbuk);
    p0_scan<<<1, 512, 0, stream>>>(bucket_cnt, bucket_base, bucket_cur, nbuk);
    p1_bucket<<<NP1, TB, 0, stream>>>(srcp, dstp, bucket_cur, pairs, E, nbuk, chunk);
    p2_csr<<<nbuk, TB, 0, stream>>>(pairs, bucket_base, row_start, deg, dinv, colx, n);
    graph_bounds<<<(G + 1 + TB - 1) / TB, TB, 0, stream>>>(batch, gstart, n, G);

    // layer 1
    matmul_mfma<F_IN><<<gMM, 256, 0, stream>>>(x, W1, dinv, xwsb, n);
    csr_gather<<<gN16, TB, 0, stream>>>(colx, row_start, deg, dinv,
                                        (const ushort4*)xwsb, b1, (float4*)bufB, n);

    // layer 2
    matmul_mfma<HDIM><<<gMM, 256, 0, stream>>>(bufB, W2, dinv, xwsb, n);
    csr_gather<<<gN16, TB, 0, stream>>>(colx, row_start, deg, dinv,
                                        (const ushort4*)xwsb, b2, (float4*)bufB, n);

    // fused pooling + head
    pool_head<<<G, 256, 0, stream>>>(bufB, gstart, Wl, bl, out, G);
}

// Round 7
// 279.972 us; speedup vs baseline: 11.8221x; 1.1014x over previous
//
#include <hip/hip_runtime.h>
#include <hip/hip_bf16.h>
#include <cmath>

#define F_IN 128
#define HDIM 64
#define NPB 256          // nodes per bucket (dst >> 8)
#define NB1 1024         // partition blocks (p0_count / p1_place grid)

typedef __attribute__((ext_vector_type(8))) short bf16x8;
typedef __attribute__((ext_vector_type(4))) float f32x4;

__device__ __forceinline__ float bf2f(unsigned short u) {
    union { unsigned int i; float f; } v; v.i = ((unsigned int)u) << 16; return v.f;
}
__device__ __forceinline__ unsigned short f2bf(float f) {
    __hip_bfloat16 h = __float2bfloat16(f);
    union { __hip_bfloat16 h; unsigned short u; } c; c.h = h; return c.u;
}

// ---------------- bucketed CSR build (atomic-free global reservation) ----------------
// bucket(d) = d >> 8 ; nbuk = ceil(n/256) = 391 <= 512
// blk_cnt layout: bucket-major [nbuk][NB1]

// P0: per-(block,bucket) histogram -> global table (no global atomics)
__launch_bounds__(256)
__global__ void p0_count(const int* __restrict__ dst, int* __restrict__ blk_cnt,
                         int E, int nbuk, int chunk) {
    __shared__ int hist[512];
    int tid = threadIdx.x;
    for (int i = tid; i < nbuk; i += 256) hist[i] = 0;
    __syncthreads();
    int lo = blockIdx.x * chunk;
    int hi = min(E, lo + chunk);
    for (int e = lo + tid; e < hi; e += 256)
        atomicAdd(&hist[dst[e] >> 8], 1);
    __syncthreads();
    for (int i = tid; i < nbuk; i += 256)
        blk_cnt[i * NB1 + blockIdx.x] = hist[i];
}

// per-bucket scan over blocks: blk_cnt row -> exclusive offsets, total -> bucket_cnt
// one WG (256 thr) per bucket; NB1=1024 -> 4 consecutive values per thread (int4).
__launch_bounds__(256)
__global__ void p_scan_blocks(int* __restrict__ blk_cnt, int* __restrict__ bucket_cnt) {
    __shared__ int sd[256];
    int b = blockIdx.x, tid = threadIdx.x;
    int4* row = (int4*)(blk_cnt + (size_t)b * NB1);
    int4 v = row[tid];
    int s0 = v.x, s1 = s0 + v.y, s2 = s1 + v.z, s3 = s2 + v.w;
    sd[tid] = s3;
    __syncthreads();
    for (int off = 1; off < 256; off <<= 1) {
        int a = (tid >= off) ? sd[tid - off] : 0;
        __syncthreads();
        sd[tid] += a;
        __syncthreads();
    }
    int base = sd[tid] - s3;   // exclusive over preceding quads
    int4 o;
    o.x = base; o.y = base + s0; o.z = base + s1; o.w = base + s2;
    row[tid] = o;
    if (tid == 255) bucket_cnt[b] = sd[255];
}

// exclusive scan of bucket totals -> bucket_base (nbuk <= 512)
__global__ void p0_scan(const int* __restrict__ cnt, int* __restrict__ base, int nbuk) {
    __shared__ int sd[512];
    int tid = threadIdx.x;
    int v = (tid < nbuk) ? cnt[tid] : 0;
    sd[tid] = v;
    __syncthreads();
    for (int off = 1; off < 512; off <<= 1) {
        int a = (tid >= off) ? sd[tid - off] : 0;
        __syncthreads();
        sd[tid] += a;
        __syncthreads();
    }
    if (tid < nbuk) base[tid] = sd[tid] - v;
    if (tid == nbuk - 1) base[nbuk] = sd[tid];   // == E
}

// P1: place edges into bucket-grouped packed ints; deterministic base, LDS-only atomics.
__launch_bounds__(256)
__global__ void p1_place(const int* __restrict__ src, const int* __restrict__ dst,
                         const int* __restrict__ blk_cnt, const int* __restrict__ bucket_base,
                         int* __restrict__ pairs, int E, int nbuk, int chunk) {
    __shared__ int cur[512];
    int tid = threadIdx.x;
    for (int i = tid; i < nbuk; i += 256)
        cur[i] = bucket_base[i] + blk_cnt[i * NB1 + blockIdx.x];
    __syncthreads();
    int lo = blockIdx.x * chunk;
    int hi = min(E, lo + chunk);
    for (int e = lo + tid; e < hi; e += 256) {
        int d = dst[e];
        int pos = atomicAdd(&cur[d >> 8], 1);
        pairs[pos] = (src[e] << 8) | (d & 255);
    }
}

// P2: one WG per bucket -> local CSR with LDS-only atomics.
__launch_bounds__(256)
__global__ void p2_csr(const int* __restrict__ pairs, const int* __restrict__ base,
                       int* __restrict__ row_start, int* __restrict__ deg,
                       float* __restrict__ dinv, int* __restrict__ col, int n) {
    __shared__ int dl[256];
    __shared__ int sc[256];
    __shared__ int cur[256];
    int b = blockIdx.x, tid = threadIdx.x;
    int nlo = b << 8;
    int eb = base[b], ee = base[b + 1];
    dl[tid] = 0;
    __syncthreads();
    for (int e = eb + tid; e < ee; e += 256)
        atomicAdd(&dl[pairs[e] & 255], 1);
    __syncthreads();
    int d0 = dl[tid];
    sc[tid] = d0;
    __syncthreads();
    for (int off = 1; off < 256; off <<= 1) {
        int a = (tid >= off) ? sc[tid - off] : 0;
        __syncthreads();
        sc[tid] += a;
        __syncthreads();
    }
    int excl = sc[tid] - d0;
    int node = nlo + tid;
    if (node < n) {
        row_start[node] = eb + excl;
        deg[node] = d0;
        dinv[node] = rsqrtf((float)(d0 + 1));
    }
    cur[tid] = eb + excl;
    __syncthreads();
    for (int e = eb + tid; e < ee; e += 256) {
        unsigned int v = (unsigned int)pairs[e];
        int pos = atomicAdd(&cur[v & 255], 1);
        col[pos] = (int)(v >> 8);
    }
}

// ---------------- graph segment boundaries (batch is sorted) ----------------

__global__ void graph_bounds(const int* __restrict__ batch, int* __restrict__ gstart,
                             int n, int G) {
    int g = blockIdx.x * blockDim.x + threadIdx.x;
    if (g > G) return;
    int lo = 0, hi = n;
    while (lo < hi) {
        int mid = (lo + hi) >> 1;
        if (batch[mid] < g) lo = mid + 1; else hi = mid;
    }
    gstart[g] = lo;
}

// ---------------- MFMA matmul: out[r,c] = bf16((X@W)[r,c] * dinv[r]) ----------------

template <int K>
__launch_bounds__(256)
__global__ void matmul_mfma(const float* __restrict__ X, const float* __restrict__ W,
                            const float* __restrict__ dinv, unsigned short* __restrict__ out,
                            int n) {
    constexpr int KS  = K / 32;
    constexpr int LDX = K + 8;
    __shared__ unsigned short Xs[64 * LDX];
    __shared__ unsigned short Wss[K * HDIM];

    int tid = threadIdx.x;
    int rowbase = blockIdx.x * 64;

    {
        const float4* W4 = (const float4*)W;
        for (int i = tid; i < K * HDIM / 4; i += 256) {
            float4 v = W4[i];
            ushort4 u = { f2bf(v.x), f2bf(v.y), f2bf(v.z), f2bf(v.w) };
            *(ushort4*)(Wss + i * 4) = u;
        }
    }
    {
        const float4* X4 = (const float4*)X;
        for (int i = tid; i < 64 * K / 4; i += 256) {
            int r = i / (K / 4), k4 = i % (K / 4);
            ushort4 u = { 0, 0, 0, 0 };
            int gr = rowbase + r;
            if (gr < n) {
                float4 v = X4[(size_t)gr * (K / 4) + k4];
                u.x = f2bf(v.x); u.y = f2bf(v.y); u.z = f2bf(v.z); u.w = f2bf(v.w);
            }
            *(ushort4*)(Xs + r * LDX + k4 * 4) = u;
        }
    }
    __syncthreads();

    int wave = tid >> 6, lane = tid & 63;
    int q = lane >> 4, nn = lane & 15;

    bf16x8 bfrag[KS][4];
#pragma unroll
    for (int s = 0; s < KS; ++s)
#pragma unroll
        for (int c = 0; c < 4; ++c) {
            short tmp[8];
#pragma unroll
            for (int j = 0; j < 8; ++j)
                tmp[j] = (short)Wss[(s * 32 + q * 8 + j) * HDIM + c * 16 + nn];
            bfrag[s][c] = *(bf16x8*)tmp;
        }

    f32x4 acc[4] = {{0,0,0,0},{0,0,0,0},{0,0,0,0},{0,0,0,0}};
    int mrow = wave * 16 + nn;
#pragma unroll
    for (int s = 0; s < KS; ++s) {
        bf16x8 af = *(const bf16x8*)(Xs + mrow * LDX + s * 32 + q * 8);
#pragma unroll
        for (int c = 0; c < 4; ++c)
            acc[c] = __builtin_amdgcn_mfma_f32_16x16x32_bf16(af, bfrag[s][c], acc[c], 0, 0, 0);
    }

#pragma unroll
    for (int r = 0; r < 4; ++r) {
        int row = rowbase + wave * 16 + q * 4 + r;
        if (row >= n) continue;
        float dv = dinv[row];
#pragma unroll
        for (int c = 0; c < 4; ++c)
            out[(size_t)row * HDIM + c * 16 + nn] = f2bf(acc[c][r] * dv);
    }
}

// ---------------- pull-mode aggregation (bf16 rows, f32 accumulate) ----------------

__global__ void csr_gather(const int* __restrict__ col, const int* __restrict__ row_start,
                           const int* __restrict__ deg, const float* __restrict__ dinv,
                           const ushort4* __restrict__ xws, const float* __restrict__ bias,
                           float4* __restrict__ out, int n) {
    int t = blockIdx.x * blockDim.x + threadIdx.x;
    int node = t >> 4;
    if (node >= n) return;
    int lane = t & 15;
    int s = row_start[node];
    int end = s + deg[node];

    ushort4 sv = xws[(size_t)node * 16 + lane];
    float4 acc = { bf2f(sv.x), bf2f(sv.y), bf2f(sv.z), bf2f(sv.w) };
    int e = s;
    for (; e + 4 <= end; e += 4) {
        int c0 = col[e], c1 = col[e + 1], c2 = col[e + 2], c3 = col[e + 3];
        ushort4 v0 = xws[(size_t)c0 * 16 + lane];
        ushort4 v1 = xws[(size_t)c1 * 16 + lane];
        ushort4 v2 = xws[(size_t)c2 * 16 + lane];
        ushort4 v3 = xws[(size_t)c3 * 16 + lane];
        acc.x += (bf2f(v0.x) + bf2f(v1.x)) + (bf2f(v2.x) + bf2f(v3.x));
        acc.y += (bf2f(v0.y) + bf2f(v1.y)) + (bf2f(v2.y) + bf2f(v3.y));
        acc.z += (bf2f(v0.z) + bf2f(v1.z)) + (bf2f(v2.z) + bf2f(v3.z));
        acc.w += (bf2f(v0.w) + bf2f(v1.w)) + (bf2f(v2.w) + bf2f(v3.w));
    }
    for (; e < end; ++e) {
        int c = col[e];
        ushort4 v = xws[(size_t)c * 16 + lane];
        acc.x += bf2f(v.x); acc.y += bf2f(v.y); acc.z += bf2f(v.z); acc.w += bf2f(v.w);
    }
    float dv = dinv[node];
    const float4 b4 = *(const float4*)(bias + lane * 4);
    float4 o;
    o.x = fmaxf(fmaf(acc.x, dv, b4.x), 0.0f);
    o.y = fmaxf(fmaf(acc.y, dv, b4.y), 0.0f);
    o.z = fmaxf(fmaf(acc.z, dv, b4.z), 0.0f);
    o.w = fmaxf(fmaf(acc.w, dv, b4.w), 0.0f);
    out[(size_t)node * 16 + lane] = o;
}

// ---------------- fused mean-pool + linear head + sigmoid ----------------

__launch_bounds__(256)
__global__ void pool_head(const float* __restrict__ h, const int* __restrict__ gstart,
                          const float* __restrict__ Wl, const float* __restrict__ bl,
                          float* __restrict__ out, int G) {
    int g = blockIdx.x;
    int s = gstart[g], e = gstart[g + 1];
    int f  = threadIdx.x & 63;
    int rg = threadIdx.x >> 6;
    float acc = 0.0f;
    for (int i = s + rg; i < e; i += 4)
        acc += h[(size_t)i * HDIM + f];
    __shared__ float red[4][HDIM];
    red[rg][f] = acc;
    __syncthreads();
    if (rg == 0) {
        float v = (red[0][f] + red[1][f]) + (red[2][f] + red[3][f]);
        float c = fmaxf((float)(e - s), 1.0f);
        v = v * Wl[f] * (1.0f / c);
#pragma unroll
        for (int off = 32; off; off >>= 1) v += __shfl_down(v, off, 64);
        if (f == 0) out[g] = 1.0f / (1.0f + expf(-(v + bl[0])));
    }
}

// ---------------- launch ----------------

extern "C" void kernel_launch(void* const* d_in, const int* in_sizes, int n_in,
                              void* d_out, int out_size, void* d_ws, size_t ws_size,
                              hipStream_t stream) {
    const float* x   = (const float*)d_in[0];
    const int* ei    = (const int*)d_in[1];
    const int* batch = (const int*)d_in[2];
    const float* W1  = (const float*)d_in[3];
    const float* b1  = (const float*)d_in[4];
    const float* W2  = (const float*)d_in[5];
    const float* b2  = (const float*)d_in[6];
    const float* Wl  = (const float*)d_in[7];
    const float* bl  = (const float*)d_in[8];
    float* out = (float*)d_out;

    const int n = in_sizes[0] / F_IN;   // 100000
    const int E = in_sizes[1] / 2;      // 1600000
    const int G = out_size;             // 512

    const int* srcp = ei;
    const int* dstp = ei + E;

    int nbuk = (n + NPB - 1) / NPB;     // 391 (<= 512)

    // workspace layout
    char* wsb = (char*)d_ws;
    auto alloc = [&](size_t bytes) { char* p = wsb; wsb += (bytes + 255) & ~(size_t)255; return p; };
    int*   deg        = (int*)alloc((size_t)n * 4);
    int*   row_start  = (int*)alloc((size_t)n * 4);
    float* dinv       = (float*)alloc((size_t)n * 4);
    int*   bucket_cnt = (int*)alloc(512 * 4);
    int*   bucket_base= (int*)alloc(513 * 4);
    int*   blk_cnt    = (int*)alloc((size_t)nbuk * NB1 * 4);   // bucket-major
    int*   pairs      = (int*)alloc((size_t)E * 4);
    int*   colx       = (int*)alloc((size_t)E * 4);
    unsigned short* xwsb = (unsigned short*)alloc((size_t)n * HDIM * 2);
    float* bufB       = (float*)alloc((size_t)n * HDIM * 4);
    int*   gstart     = (int*)alloc(((size_t)G + 1) * 4);

    const int TB = 256;
    int gN16 = (n * 16 + TB - 1) / TB;
    int gMM  = (n + 63) / 64;
    int chunk = (E + NB1 - 1) / NB1;   // 1563

    // bucketed CSR build (no global atomics)
    p0_count<<<NB1, TB, 0, stream>>>(dstp, blk_cnt, E, nbuk, chunk);
    p_scan_blocks<<<nbuk, TB, 0, stream>>>(blk_cnt, bucket_cnt);
    p0_scan<<<1, 512, 0, stream>>>(bucket_cnt, bucket_base, nbuk);
    p1_place<<<NB1, TB, 0, stream>>>(srcp, dstp, blk_cnt, bucket_base, pairs, E, nbuk, chunk);
    p2_csr<<<nbuk, TB, 0, stream>>>(pairs, bucket_base, row_start, deg, dinv, colx, n);
    graph_bounds<<<(G + 1 + TB - 1) / TB, TB, 0, stream>>>(batch, gstart, n, G);

    // layer 1
    matmul_mfma<F_IN><<<gMM, 256, 0, stream>>>(x, W1, dinv, xwsb, n);
    csr_gather<<<gN16, TB, 0, stream>>>(colx, row_start, deg, dinv,
                                        (const ushort4*)xwsb, b1, (float4*)bufB, n);

    // layer 2
    matmul_mfma<HDIM><<<gMM, 256, 0, stream>>>(bufB, W2, dinv, xwsb, n);
    csr_gather<<<gN16, TB, 0, stream>>>(colx, row_start, deg, dinv,
                                        (const ushort4*)xwsb, b2, (float4*)bufB, n);

    // fused pooling + head
    pool_head<<<G, 256, 0, stream>>>(bufB, gstart, Wl, bl, out, G);
}